// Round 1
// baseline (154.368 us; speedup 1.0000x reference)
//
#include <hip/hip_runtime.h>
#include <hip/hip_bf16.h>

#define K_NEIGH 10
#define D_DIM   256   // floats per row = 64 float4 = one wave's worth

__global__ __launch_bounds__(256) void mean_agg_kernel(
    const int* __restrict__ idx,          // [N, 10] int32
    const float* __restrict__ embed,      // [M, 256] f32
    float* __restrict__ out,              // [N, 256] f32
    int n_nodes)
{
    const int wave = threadIdx.x >> 6;            // 4 waves per block
    const int lane = threadIdx.x & 63;            // lane owns one float4 (16B) of the row
    const int node = blockIdx.x * 4 + wave;
    if (node >= n_nodes) return;

    // Wave-uniform neighbor ids (broadcast loads; compiler can scalarize)
    const int* nidx = idx + (size_t)node * K_NEIGH;

    float4 acc = make_float4(0.f, 0.f, 0.f, 0.f);
    #pragma unroll
    for (int k = 0; k < K_NEIGH; ++k) {
        const int r = nidx[k];
        const float4 v =
            reinterpret_cast<const float4*>(embed + (size_t)r * D_DIM)[lane];
        acc.x += v.x; acc.y += v.y; acc.z += v.z; acc.w += v.w;
    }

    const float s = 1.0f / (float)K_NEIGH;
    acc.x *= s; acc.y *= s; acc.z *= s; acc.w *= s;

    reinterpret_cast<float4*>(out + (size_t)node * D_DIM)[lane] = acc;
}

extern "C" void kernel_launch(void* const* d_in, const int* in_sizes, int n_in,
                              void* d_out, int out_size, void* d_ws, size_t ws_size,
                              hipStream_t stream) {
    const int*   idx   = (const int*)d_in[0];     // neighbor_idx [N,10]
    const float* embed = (const float*)d_in[1];   // embed_matrix [M,256]
    float*       out   = (float*)d_out;           // [N,256]

    const int n_nodes = in_sizes[0] / K_NEIGH;    // 100000
    const int nodes_per_block = 4;                // 4 waves x 64 lanes
    const int grid = (n_nodes + nodes_per_block - 1) / nodes_per_block;

    mean_agg_kernel<<<grid, 256, 0, stream>>>(idx, embed, out, n_nodes);
}

// Round 2
// 151.905 us; speedup vs baseline: 1.0162x; 1.0162x over previous
//
#include <hip/hip_runtime.h>
#include <hip/hip_bf16.h>

#define K_NEIGH 10
#define D_DIM   256   // floats per row = 64 float4 = one wave's worth

typedef float f32x4 __attribute__((ext_vector_type(4)));

__global__ __launch_bounds__(256) void mean_agg_kernel(
    const int* __restrict__ idx,          // [N, 10] int32
    const float* __restrict__ embed,      // [M, 256] f32
    float* __restrict__ out,              // [N, 256] f32
    int n_nodes)
{
    const int wave = threadIdx.x >> 6;            // 4 waves per block
    const int lane = threadIdx.x & 63;            // lane owns one float4 (16B) of the row
    const int node = blockIdx.x * 4 + wave;
    if (node >= n_nodes) return;

    // Neighbor ids: read once, nontemporal (don't pollute L2 with idx lines)
    const int* nidx = idx + (size_t)node * K_NEIGH;
    int r0 = __builtin_nontemporal_load(nidx + 0);
    int r1 = __builtin_nontemporal_load(nidx + 1);
    int r2 = __builtin_nontemporal_load(nidx + 2);
    int r3 = __builtin_nontemporal_load(nidx + 3);
    int r4 = __builtin_nontemporal_load(nidx + 4);
    int r5 = __builtin_nontemporal_load(nidx + 5);
    int r6 = __builtin_nontemporal_load(nidx + 6);
    int r7 = __builtin_nontemporal_load(nidx + 7);
    int r8 = __builtin_nontemporal_load(nidx + 8);
    int r9 = __builtin_nontemporal_load(nidx + 9);

    const f32x4* __restrict__ e = (const f32x4*)embed;
    // Issue all 10 row loads before consuming any — named values with static
    // indexing so they live in VGPRs and all 10 stay in flight (MLP).
    f32x4 v0 = e[(size_t)r0 * 64 + lane];
    f32x4 v1 = e[(size_t)r1 * 64 + lane];
    f32x4 v2 = e[(size_t)r2 * 64 + lane];
    f32x4 v3 = e[(size_t)r3 * 64 + lane];
    f32x4 v4 = e[(size_t)r4 * 64 + lane];
    f32x4 v5 = e[(size_t)r5 * 64 + lane];
    f32x4 v6 = e[(size_t)r6 * 64 + lane];
    f32x4 v7 = e[(size_t)r7 * 64 + lane];
    f32x4 v8 = e[(size_t)r8 * 64 + lane];
    f32x4 v9 = e[(size_t)r9 * 64 + lane];

    // Pairwise tree sum (consumes in arrival order reasonably well)
    f32x4 s01 = v0 + v1;
    f32x4 s23 = v2 + v3;
    f32x4 s45 = v4 + v5;
    f32x4 s67 = v6 + v7;
    f32x4 s89 = v8 + v9;
    f32x4 acc = ((s01 + s23) + (s45 + s67)) + s89;
    acc *= 0.1f;

    // Nontemporal store: out is write-once streaming; don't let 100 MB of
    // write-allocate traffic evict embed rows from the 4 MB per-XCD L2s.
    __builtin_nontemporal_store(acc, (f32x4*)(out + (size_t)node * D_DIM) + lane);
}

extern "C" void kernel_launch(void* const* d_in, const int* in_sizes, int n_in,
                              void* d_out, int out_size, void* d_ws, size_t ws_size,
                              hipStream_t stream) {
    const int*   idx   = (const int*)d_in[0];     // neighbor_idx [N,10]
    const float* embed = (const float*)d_in[1];   // embed_matrix [M,256]
    float*       out   = (float*)d_out;           // [N,256]

    const int n_nodes = in_sizes[0] / K_NEIGH;    // 100000
    const int nodes_per_block = 4;                // 4 waves x 64 lanes
    const int grid = (n_nodes + nodes_per_block - 1) / nodes_per_block;

    mean_agg_kernel<<<grid, 256, 0, stream>>>(idx, embed, out, n_nodes);
}